// Round 1
// baseline (94.293 us; speedup 1.0000x reference)
//
#include <hip/hip_runtime.h>
#include <hip/hip_bf16.h>

typedef __bf16 bf16x8 __attribute__((ext_vector_type(8)));
typedef float  f32x4  __attribute__((ext_vector_type(4)));

#define NB    512
#define SEQ   128
#define EMB   300
#define NFILT 100
#define NPAD  128

// packed-weight sizes (elements) per kernel size: NPAD * (k*320)
#define TOT3 (NPAD * 960)
#define TOT4 (NPAD * 1280)
#define TOT5 (NPAD * 1600)
// ws byte offsets
#define OFF_WF3 0
#define OFF_WF4 (OFF_WF3 + TOT3 * 2)
#define OFF_WF5 (OFF_WF4 + TOT4 * 2)
#define OFF_FEATS (OFF_WF5 + TOT5 * 2)   // 983040; feats = 512*300 f32

__device__ __forceinline__ unsigned short f2bf(float f) {
  unsigned u = __builtin_bit_cast(unsigned, f);
  unsigned r = (u + 0x7fffu + ((u >> 16) & 1u)) >> 16;   // RNE, inputs are normal
  return (unsigned short)r;
}

// Pack conv weights into MFMA B-fragment order, bf16, zero-padded (E->320, NF->128).
// Layout: idx = ((nt*NKT + kt)*64 + lane)*8 + j  ->  W[f = nt*16 + (lane&15)][kk = kt*32 + (lane>>4)*8 + j]
__global__ void prep_weights(const float* __restrict__ w3, const float* __restrict__ w4,
                             const float* __restrict__ w5, unsigned short* __restrict__ ws) {
  int idx = blockIdx.x * blockDim.x + threadIdx.x;
  const float* src; unsigned short* dst; int ksz, nkt, idx2;
  if (idx < TOT3)               { src = w3; dst = ws;                ksz = 3; nkt = 30; idx2 = idx; }
  else if (idx < TOT3 + TOT4)   { src = w4; dst = ws + TOT3;        ksz = 4; nkt = 40; idx2 = idx - TOT3; }
  else if (idx < TOT3+TOT4+TOT5){ src = w5; dst = ws + TOT3 + TOT4; ksz = 5; nkt = 50; idx2 = idx - TOT3 - TOT4; }
  else return;
  int j  = idx2 & 7;
  int l  = (idx2 >> 3) & 63;
  int t  = idx2 >> 9;
  int kt = t % nkt, nt = t / nkt;
  int f  = nt * 16 + (l & 15);
  int kk = kt * 32 + ((l >> 4) << 3) + j;
  int dk = kk / 320, e = kk - dk * 320;
  float v = 0.f;
  if (f < NFILT && e < EMB) v = src[(f * ksz + dk) * EMB + e];
  dst[idx2] = f2bf(v);
}

// One conv branch (kernel size KSZ) computed from the staged LDS x-tile.
// Wave layout: 4 waves; wave w owns N-tiles {2w, 2w+1}; every wave covers all 4 M-tiles (64 s-positions).
template<int KSZ>
__device__ __forceinline__ void conv_branch(const unsigned short* xs,
                                            const unsigned short* __restrict__ wf,
                                            const float* __restrict__ bias,
                                            float* __restrict__ feats_b,
                                            int s0, int l, int w) {
  constexpr int PAD  = KSZ - 3;          // 0,1,2
  constexpr int NKT  = KSZ * 10;         // K-steps of 32
  constexpr int SVAL = 123 + KSZ;        // valid output positions: 126,127,128
  const int lo = l & 15, hi = l >> 4;

  f32x4 acc[4][2];
  #pragma unroll
  for (int mt = 0; mt < 4; ++mt) {
    acc[mt][0] = (f32x4){0.f, 0.f, 0.f, 0.f};
    acc[mt][1] = (f32x4){0.f, 0.f, 0.f, 0.f};
  }

  const unsigned short* bp0 = wf + (2 * w) * NKT * 512 + l * 8;
  const unsigned short* bp1 = bp0 + NKT * 512;

  #pragma unroll
  for (int dk = 0; dk < KSZ; ++dk) {
    #pragma unroll 2
    for (int kt2 = 0; kt2 < 10; ++kt2) {
      const int kt = dk * 10 + kt2;
      bf16x8 b0 = *(const bf16x8*)(bp0 + kt * 512);
      bf16x8 b1 = *(const bf16x8*)(bp1 + kt * 512);
      #pragma unroll
      for (int mt = 0; mt < 4; ++mt) {
        int row = (2 - PAD) + lo + mt * 16 + dk;          // staged xs row for this A element
        int boff = ((row * 320 + kt2 * 32 + hi * 8) * 2) ^ ((row & 7) << 4);
        bf16x8 a = *(const bf16x8*)((const char*)xs + boff);
        acc[mt][0] = __builtin_amdgcn_mfma_f32_16x16x32_bf16(a, b0, acc[mt][0], 0, 0, 0);
        acc[mt][1] = __builtin_amdgcn_mfma_f32_16x16x32_bf16(a, b1, acc[mt][1], 0, 0, 0);
      }
    }
  }

  // bias + relu + masked max over this block's 64 s-positions, then column-reduce + atomicMax
  #pragma unroll
  for (int ni = 0; ni < 2; ++ni) {
    int f = (2 * w + ni) * 16 + lo;
    float bia = (f < NFILT) ? bias[f] : 0.f;
    float cmax = 0.f;                                     // relu floor
    #pragma unroll
    for (int mt = 0; mt < 4; ++mt) {
      #pragma unroll
      for (int i = 0; i < 4; ++i) {
        int s = s0 + mt * 16 + hi * 4 + i;                // C/D: row=(lane>>4)*4+i, col=lane&15
        float v = acc[mt][ni][i] + bia;
        if (s < SVAL) cmax = fmaxf(cmax, v);
      }
    }
    cmax = fmaxf(cmax, __shfl_xor(cmax, 16));
    cmax = fmaxf(cmax, __shfl_xor(cmax, 32));
    if (hi == 0 && f < NFILT)
      atomicMax((int*)&feats_b[f], __float_as_int(fmaxf(cmax, 0.f)));
  }
}

__global__ __launch_bounds__(256, 2)
void conv_max_kernel(const float* __restrict__ x, const unsigned short* __restrict__ wsw,
                     const float* __restrict__ b3, const float* __restrict__ b4,
                     const float* __restrict__ b5, float* __restrict__ feats) {
  __shared__ __align__(16) unsigned short xs[68 * 320];   // rows s0-2 .. s0+65, E padded to 320, bf16
  const int bid = blockIdx.x;
  const int b = bid >> 1, s0 = (bid & 1) * 64;
  const int tid = threadIdx.x;

  // stage x tile: fp32 -> bf16, zero pad (rows outside [0,128) and cols 300..319), XOR-swizzled
  for (int t = tid; t < 68 * 80; t += 256) {
    int r = t / 80, cg = t - r * 80;                      // 4 cols per task
    int xr = s0 - 2 + r;
    float4 v = make_float4(0.f, 0.f, 0.f, 0.f);
    if (xr >= 0 && xr < SEQ && cg < 75)
      v = *reinterpret_cast<const float4*>(x + ((size_t)b * SEQ + xr) * EMB + cg * 4);
    ushort4 h;
    h.x = f2bf(v.x); h.y = f2bf(v.y); h.z = f2bf(v.z); h.w = f2bf(v.w);
    int boff = (r * 640 + cg * 8) ^ ((r & 7) << 4);
    *reinterpret_cast<ushort4*>((char*)xs + boff) = h;
  }
  __syncthreads();

  const int l = tid & 63, w = tid >> 6;
  float* feats_b = feats + b * 300;
  conv_branch<3>(xs, wsw + (OFF_WF3 / 2), b3, feats_b +   0, s0, l, w);
  conv_branch<4>(xs, wsw + (OFF_WF4 / 2), b4, feats_b + 100, s0, l, w);
  conv_branch<5>(xs, wsw + (OFF_WF5 / 2), b5, feats_b + 200, s0, l, w);
}

// feats[512,300] @ Wfc[5,300]^T + bfc -> log_softmax. One wave per row.
__global__ void fc_kernel(const float* __restrict__ feats, const float* __restrict__ Wfc,
                          const float* __restrict__ bfc, float* __restrict__ out) {
  const int b = blockIdx.x, l = threadIdx.x;
  float acc[5] = {0.f, 0.f, 0.f, 0.f, 0.f};
  for (int e = l; e < 300; e += 64) {
    float fv = feats[b * 300 + e];
    #pragma unroll
    for (int c = 0; c < 5; ++c) acc[c] += fv * Wfc[c * 300 + e];
  }
  #pragma unroll
  for (int off = 32; off; off >>= 1) {
    #pragma unroll
    for (int c = 0; c < 5; ++c) acc[c] += __shfl_down(acc[c], off);
  }
  if (l == 0) {
    float lg[5], m = -1e30f;
    #pragma unroll
    for (int c = 0; c < 5; ++c) { lg[c] = acc[c] + bfc[c]; m = fmaxf(m, lg[c]); }
    float se = 0.f;
    #pragma unroll
    for (int c = 0; c < 5; ++c) se += expf(lg[c] - m);
    float ls = logf(se);
    #pragma unroll
    for (int c = 0; c < 5; ++c) out[b * 5 + c] = lg[c] - m - ls;
  }
}

extern "C" void kernel_launch(void* const* d_in, const int* in_sizes, int n_in,
                              void* d_out, int out_size, void* d_ws, size_t ws_size,
                              hipStream_t stream) {
  const float* x   = (const float*)d_in[0];
  const float* w3  = (const float*)d_in[1];
  const float* b3  = (const float*)d_in[2];
  const float* w4  = (const float*)d_in[3];
  const float* b4  = (const float*)d_in[4];
  const float* w5  = (const float*)d_in[5];
  const float* b5  = (const float*)d_in[6];
  const float* Wfc = (const float*)d_in[7];
  const float* bfc = (const float*)d_in[8];
  float* out = (float*)d_out;

  unsigned short* wsp = (unsigned short*)d_ws;
  float* feats = (float*)((char*)d_ws + OFF_FEATS);

  hipMemsetAsync(feats, 0, NB * 300 * sizeof(float), stream);   // atomicMax target, relu floor = 0

  int tot = TOT3 + TOT4 + TOT5;
  prep_weights<<<(tot + 255) / 256, 256, 0, stream>>>(w3, w4, w5, wsp);
  conv_max_kernel<<<NB * 2, 256, 0, stream>>>(x, wsp, b3, b4, b5, feats);
  fc_kernel<<<NB, 64, 0, stream>>>(feats, Wfc, bfc, out);
}